// Round 1
// baseline (646.089 us; speedup 1.0000x reference)
//
#include <hip/hip_runtime.h>
#include <hip/hip_bf16.h>
#include <math.h>

#define B 2048
#define L 100
#define D 256

typedef _Float16 half8 __attribute__((ext_vector_type(8)));
typedef __attribute__((ext_vector_type(4))) float f32x4;

// ---------------------------------------------------------------------------
// K0: abs_w[t] = abs_embed[t]·w_abs, relw[i] = rel_embed[i]·w_rel,
//     exclusive scan of doc_lens.
// ---------------------------------------------------------------------------
__global__ __launch_bounds__(256) void k0_precompute(
    const float* __restrict__ abs_embed, const float* __restrict__ w_abs,
    const float* __restrict__ rel_embed, const float* __restrict__ w_rel,
    const int* __restrict__ dls,
    float* __restrict__ abs_w, float* __restrict__ relw, int* __restrict__ offs)
{
    int t = threadIdx.x;
    if (t < 100) {
        float s = 0.f;
        for (int j = 0; j < 50; j++) s += abs_embed[t * 50 + j] * w_abs[j];
        abs_w[t] = s;
    }
    if (t < 25) {
        float s = 0.f;
        for (int j = 0; j < 50; j++) s += rel_embed[t * 50 + j] * w_rel[j];
        relw[t] = s;
    }
    __shared__ int lds[256];
    int loc[8];
    int sum = 0;
    for (int k = 0; k < 8; k++) { loc[k] = sum; sum += dls[t * 8 + k]; }
    lds[t] = sum;
    __syncthreads();
    for (int off = 1; off < 256; off <<= 1) {
        int v = (t >= off) ? lds[t - off] : 0;
        __syncthreads();
        lds[t] += v;
        __syncthreads();
    }
    int base = (t > 0) ? lds[t - 1] : 0;
    for (int k = 0; k < 8; k++) offs[t * 8 + k] = base + loc[k];
}

// ---------------------------------------------------------------------------
// K0b: split-fp16 transpose of W_nov: Wh/Wl are [N][K] fp16,
//      W = Wh + Wl with |err| <= 2^-22 rel.  (2 x 128 KB, L2-resident)
// ---------------------------------------------------------------------------
__global__ __launch_bounds__(256) void k0b_wt(
    const float* __restrict__ W, _Float16* __restrict__ Wh, _Float16* __restrict__ Wl)
{
    int n = blockIdx.x, k = threadIdx.x;
    float w = W[k * D + n];
    _Float16 hi = (_Float16)w;
    _Float16 lo = (_Float16)(w - (float)hi);
    Wh[n * D + k] = hi;
    Wl[n * D + k] = lo;
}

// ---------------------------------------------------------------------------
// K1: docs[b,d] = sum_{t<dl} sent[b,t,d] / dl   (one block per doc)
// ---------------------------------------------------------------------------
__global__ __launch_bounds__(256) void k1_docavg(
    const float* __restrict__ sent, const int* __restrict__ dls,
    float* __restrict__ docs)
{
    int b = blockIdx.x, d = threadIdx.x;
    int dl = dls[b];
    const float* p = sent + (size_t)b * L * D + d;
    float s = 0.f;
    int t = 0;
    for (; t + 4 <= dl; t += 4) {
        s += p[(size_t)t * D] + p[(size_t)(t + 1) * D] +
             p[(size_t)(t + 2) * D] + p[(size_t)(t + 3) * D];
    }
    for (; t < dl; t++) s += p[(size_t)t * D];
    docs[b * D + d] = s / (float)dl;
}

// ---------------------------------------------------------------------------
// K2: doc = tanh(docs @ fc_w.T + fc_b); uw = W_sal @ doc + w_content
//     8 docs per block: weight rows read once per block, reused 8x.
// ---------------------------------------------------------------------------
__global__ __launch_bounds__(256) void k2_docrep(
    const float* __restrict__ docs, const float* __restrict__ fc_w,
    const float* __restrict__ fc_b, const float* __restrict__ W_sal,
    const float* __restrict__ w_content, float* __restrict__ uw)
{
    __shared__ float sd[8][D];
    __shared__ float sdoc[8][D];
    int g = blockIdx.x;
    int i = threadIdx.x;

    for (int dd = 0; dd < 8; dd++) sd[dd][i] = docs[(size_t)(g * 8 + dd) * D + i];
    __syncthreads();

    float acc[8];
    float fb = fc_b[i];
#pragma unroll
    for (int dd = 0; dd < 8; dd++) acc[dd] = fb;
    const float4* wr = (const float4*)(fc_w + (size_t)i * D);
    for (int j = 0; j < D / 4; j++) {
        float4 w = wr[j];
#pragma unroll
        for (int dd = 0; dd < 8; dd++) {
            float4 v = ((const float4*)sd[dd])[j];
            acc[dd] += w.x * v.x + w.y * v.y + w.z * v.z + w.w * v.w;
        }
    }
#pragma unroll
    for (int dd = 0; dd < 8; dd++) sdoc[dd][i] = tanhf(acc[dd]);
    __syncthreads();

    float acc2[8];
#pragma unroll
    for (int dd = 0; dd < 8; dd++) acc2[dd] = 0.f;
    const float4* wsr = (const float4*)(W_sal + (size_t)i * D);
    for (int j = 0; j < D / 4; j++) {
        float4 w = wsr[j];
#pragma unroll
        for (int dd = 0; dd < 8; dd++) {
            float4 v = ((const float4*)sdoc[dd])[j];
            acc2[dd] += w.x * v.x + w.y * v.y + w.z * v.z + w.w * v.w;
        }
    }
    float wc = w_content[i];
#pragma unroll
    for (int dd = 0; dd < 8; dd++)
        uw[(size_t)(g * 8 + dd) * D + i] = acc2[dd] + wc;
}

// ---------------------------------------------------------------------------
// K3: G(fp32) = sent @ W_nov via split-fp16 MFMA (hi*hi + hi*lo + lo*hi).
//     NO LDS, NO barriers: each lane loads its A fragment (8 contiguous fp32,
//     32 B) directly from global, splits to fp16 planes in registers, and
//     streams MFMAs. B fragments come straight from L2-resident Wh/Wl.
//     128x128 tile, 4 waves x 64x64 quadrants. Accumulation order identical
//     to the previous LDS version -> bit-identical G.
// ---------------------------------------------------------------------------
__global__ __launch_bounds__(256) void k3_mfma(
    const float* __restrict__ A, const _Float16* __restrict__ Wh,
    const _Float16* __restrict__ Wl, float* __restrict__ G)
{
    int tid = threadIdx.x;
    int lane = tid & 63;
    int wv = tid >> 6;
    int n0 = blockIdx.x * 128;           // gridDim.x = 2 (n fastest -> L2-hot A)
    int m0 = blockIdx.y * 128;
    int m_off = (wv & 1) * 64;
    int n_off = (wv >> 1) * 64;
    int quad = lane >> 4;
    int l15 = lane & 15;

    f32x4 acc[4][4];
#pragma unroll
    for (int fi = 0; fi < 4; fi++)
#pragma unroll
        for (int fj = 0; fj < 4; fj++) acc[fi][fj] = (f32x4){0.f, 0.f, 0.f, 0.f};

    // lane-private fragment base pointers (k offset = quad*8 within granule)
    const float*    a0  = A  + (size_t)(m0 + m_off + l15) * D + quad * 8;
    const _Float16* bh0 = Wh + (size_t)(n0 + n_off + l15) * D + quad * 8;
    const _Float16* bl0 = Wl + (size_t)(n0 + n_off + l15) * D + quad * 8;

#pragma unroll 2
    for (int ki = 0; ki < 8; ki++) {     // K granule of 32: k = ki*32
        half8 ah[4], al[4], bh[4], bl[4];
#pragma unroll
        for (int fj = 0; fj < 4; fj++) {
            bh[fj] = *(const half8*)(bh0 + (size_t)fj * 16 * D + ki * 32);
            bl[fj] = *(const half8*)(bl0 + (size_t)fj * 16 * D + ki * 32);
        }
#pragma unroll
        for (int fi = 0; fi < 4; fi++) {
            const float* p = a0 + (size_t)fi * 16 * D + ki * 32;
            float4 v0 = *(const float4*)p;
            float4 v1 = *(const float4*)(p + 4);
            float f[8] = {v0.x, v0.y, v0.z, v0.w, v1.x, v1.y, v1.z, v1.w};
#pragma unroll
            for (int j = 0; j < 8; j++) {
                _Float16 h = (_Float16)f[j];
                ah[fi][j] = h;
                al[fi][j] = (_Float16)(f[j] - (float)h);
            }
        }
#pragma unroll
        for (int fi = 0; fi < 4; fi++)
#pragma unroll
            for (int fj = 0; fj < 4; fj++) {
                acc[fi][fj] = __builtin_amdgcn_mfma_f32_16x16x32_f16(
                    ah[fi], bh[fj], acc[fi][fj], 0, 0, 0);
                acc[fi][fj] = __builtin_amdgcn_mfma_f32_16x16x32_f16(
                    ah[fi], bl[fj], acc[fi][fj], 0, 0, 0);
                acc[fi][fj] = __builtin_amdgcn_mfma_f32_16x16x32_f16(
                    al[fi], bh[fj], acc[fi][fj], 0, 0, 0);
            }
    }

    // ---- epilogue: direct fp32 stores (C layout: row=quad*4+q, col=l15) ----
#pragma unroll
    for (int fi = 0; fi < 4; fi++)
#pragma unroll
        for (int fj = 0; fj < 4; fj++)
#pragma unroll
            for (int q = 0; q < 4; q++) {
                int row = m0 + m_off + fi * 16 + quad * 4 + q;
                int col = n0 + n_off + fj * 16 + l15;
                G[(size_t)row * D + col] = acc[fi][fj][q];
            }
}

// ---------------------------------------------------------------------------
// K4: recurrence. One wave per doc; lane l owns dims 4l..4l+3 of s.
//     Depth-4 prefetch: t-loop unrolled x4 with static h/g register pairs;
//     row t+4 is issued at step t (4 steps ~ 1000+ cyc to cover HBM latency).
//     Tail steps (t >= dl) are predicated out of s-update and the store.
// ---------------------------------------------------------------------------
__global__ __launch_bounds__(256) void k4_recur(
    const float* __restrict__ sent, const float* __restrict__ G,
    const float* __restrict__ uw, const float* __restrict__ abs_w,
    const float* __restrict__ relw, const float* __restrict__ bias,
    const int* __restrict__ dls, const int* __restrict__ offs,
    float* __restrict__ out)
{
    int wave = threadIdx.x >> 6;
    int lane = threadIdx.x & 63;
    int b = blockIdx.x * 4 + wave;

    int dl = dls[b];
    float dlf = (float)dl;
    int base = offs[b];
    float bs = bias[0];

    const float4* h_ptr = (const float4*)(sent + (size_t)b * L * D) + lane;
    const float4* g_ptr = (const float4*)(G + (size_t)b * L * D) + lane;
    float4 uwv = ((const float4*)(uw + (size_t)b * D))[lane];

    float4 s = make_float4(0.f, 0.f, 0.f, 0.f);

    // prologue: rows 0..3 (always inside the [L][D] allocation; rows >= dl
    // hold real finite data and are masked out below)
    float4 h0 = h_ptr[0 * (D / 4)], g0 = g_ptr[0 * (D / 4)];
    float4 h1 = h_ptr[1 * (D / 4)], g1 = g_ptr[1 * (D / 4)];
    float4 h2 = h_ptr[2 * (D / 4)], g2 = g_ptr[2 * (D / 4)];
    float4 h3 = h_ptr[3 * (D / 4)], g3 = g_ptr[3 * (D / 4)];

#define STEP(HH, GG, TT)                                                     \
    {                                                                        \
        int tt = (TT);                                                       \
        int tp = tt + 4; if (tp >= L) tp = 0;                                \
        float4 hn = h_ptr[(size_t)tp * (D / 4)];                             \
        float4 gn = g_ptr[(size_t)tp * (D / 4)];                             \
        float4 ts;                                                           \
        ts.x = tanhf(s.x); ts.y = tanhf(s.y);                                \
        ts.z = tanhf(s.z); ts.w = tanhf(s.w);                                \
        float r = HH.x * uwv.x + HH.y * uwv.y + HH.z * uwv.z + HH.w * uwv.w  \
                - (GG.x * ts.x + GG.y * ts.y + GG.z * ts.z + GG.w * ts.w);   \
        r += __shfl_xor(r, 32, 64);                                          \
        r += __shfl_xor(r, 16, 64);                                          \
        r += __shfl_xor(r, 8, 64);                                           \
        r += __shfl_xor(r, 4, 64);                                           \
        r += __shfl_xor(r, 2, 64);                                           \
        r += __shfl_xor(r, 1, 64);                                           \
        bool valid = tt < dl;                                                \
        int ta = valid ? tt : 0;                                             \
        int idx = (int)rintf((float)(tt + 1) * 9.0f / dlf);                  \
        if (idx > 24) idx = 24;                                              \
        float pre = r + abs_w[ta] + relw[idx] + bs;                          \
        float p = 1.0f / (1.0f + __expf(-pre));                              \
        float pm = valid ? p : 0.0f;                                         \
        s.x += pm * HH.x; s.y += pm * HH.y;                                  \
        s.z += pm * HH.z; s.w += pm * HH.w;                                  \
        if (valid && lane == 0) out[base + tt] = p;                          \
        HH = hn; GG = gn;                                                    \
    }

    int nsteps = (dl + 3) & ~3;
    for (int t = 0; t < nsteps; t += 4) {
        STEP(h0, g0, t);
        STEP(h1, g1, t + 1);
        STEP(h2, g2, t + 2);
        STEP(h3, g3, t + 3);
    }
#undef STEP
}

// ---------------------------------------------------------------------------
extern "C" void kernel_launch(void* const* d_in, const int* in_sizes, int n_in,
                              void* d_out, int out_size, void* d_ws, size_t ws_size,
                              hipStream_t stream)
{
    const float* sent      = (const float*)d_in[0];
    const float* fc_w      = (const float*)d_in[1];
    const float* fc_b      = (const float*)d_in[2];
    const float* w_content = (const float*)d_in[3];
    const float* W_sal     = (const float*)d_in[4];
    const float* W_nov     = (const float*)d_in[5];
    const float* abs_embed = (const float*)d_in[6];
    const float* rel_embed = (const float*)d_in[7];
    const float* w_abs     = (const float*)d_in[8];
    const float* w_rel     = (const float*)d_in[9];
    const float* bias      = (const float*)d_in[10];
    const int*   dls       = (const int*)d_in[11];
    float* out = (float*)d_out;

    // workspace layout (bytes)
    char* ws = (char*)d_ws;
    int*      offs  = (int*)ws;                                   // 8 KiB
    float*    abs_w = (float*)(ws + 8192);                        // 512 B
    float*    relw  = (float*)(ws + 8704);                        // 512 B
    float*    docs  = (float*)(ws + 9216);                        // 2 MiB
    float*    uw    = (float*)(ws + 9216 + (size_t)B * D * 4);    // 2 MiB
    _Float16* Wh    = (_Float16*)(ws + 9216 + 2 * (size_t)B * D * 4);          // 128 KiB
    _Float16* Wl    = (_Float16*)(ws + 9216 + 2 * (size_t)B * D * 4 + 131072); // 128 KiB
    float*    G     = (float*)(ws + 9216 + 2 * (size_t)B * D * 4 + 262144);    // 200 MiB

    hipLaunchKernelGGL(k0_precompute, dim3(1), dim3(256), 0, stream,
                       abs_embed, w_abs, rel_embed, w_rel, dls, abs_w, relw, offs);
    hipLaunchKernelGGL(k0b_wt, dim3(D), dim3(D), 0, stream, W_nov, Wh, Wl);
    hipLaunchKernelGGL(k1_docavg, dim3(B), dim3(256), 0, stream, sent, dls, docs);
    hipLaunchKernelGGL(k2_docrep, dim3(B / 8), dim3(256), 0, stream,
                       docs, fc_w, fc_b, W_sal, w_content, uw);
    hipLaunchKernelGGL(k3_mfma, dim3(2, (B * L) / 128), dim3(256), 0, stream,
                       sent, Wh, Wl, G);
    hipLaunchKernelGGL(k4_recur, dim3(B / 4), dim3(256), 0, stream,
                       sent, G, uw, abs_w, relw, bias, dls, offs, out);
}

// Round 3
// 576.821 us; speedup vs baseline: 1.1201x; 1.1201x over previous
//
#include <hip/hip_runtime.h>
#include <hip/hip_bf16.h>
#include <math.h>

#define B 2048
#define L 100
#define D 256

typedef _Float16 half8 __attribute__((ext_vector_type(8)));
typedef __attribute__((ext_vector_type(4))) float f32x4;

// ---------------------------------------------------------------------------
// K0: abs_w[t] = abs_embed[t]·w_abs, relw[i] = rel_embed[i]·w_rel,
//     exclusive scan of doc_lens.
// ---------------------------------------------------------------------------
__global__ __launch_bounds__(256) void k0_precompute(
    const float* __restrict__ abs_embed, const float* __restrict__ w_abs,
    const float* __restrict__ rel_embed, const float* __restrict__ w_rel,
    const int* __restrict__ dls,
    float* __restrict__ abs_w, float* __restrict__ relw, int* __restrict__ offs)
{
    int t = threadIdx.x;
    if (t < 100) {
        float s = 0.f;
        for (int j = 0; j < 50; j++) s += abs_embed[t * 50 + j] * w_abs[j];
        abs_w[t] = s;
    }
    if (t < 25) {
        float s = 0.f;
        for (int j = 0; j < 50; j++) s += rel_embed[t * 50 + j] * w_rel[j];
        relw[t] = s;
    }
    __shared__ int lds[256];
    int loc[8];
    int sum = 0;
    for (int k = 0; k < 8; k++) { loc[k] = sum; sum += dls[t * 8 + k]; }
    lds[t] = sum;
    __syncthreads();
    for (int off = 1; off < 256; off <<= 1) {
        int v = (t >= off) ? lds[t - off] : 0;
        __syncthreads();
        lds[t] += v;
        __syncthreads();
    }
    int base = (t > 0) ? lds[t - 1] : 0;
    for (int k = 0; k < 8; k++) offs[t * 8 + k] = base + loc[k];
}

// ---------------------------------------------------------------------------
// K0b: split-fp16 transpose of W_nov: Wh/Wl are [N][K] fp16,
//      W = Wh + Wl with |err| <= 2^-22 rel.  (2 x 128 KB, L2-resident)
// ---------------------------------------------------------------------------
__global__ __launch_bounds__(256) void k0b_wt(
    const float* __restrict__ W, _Float16* __restrict__ Wh, _Float16* __restrict__ Wl)
{
    int n = blockIdx.x, k = threadIdx.x;
    float w = W[k * D + n];
    _Float16 hi = (_Float16)w;
    _Float16 lo = (_Float16)(w - (float)hi);
    Wh[n * D + k] = hi;
    Wl[n * D + k] = lo;
}

// ---------------------------------------------------------------------------
// K1: docs[b,d] = sum_{t<dl} sent[b,t,d] / dl
//     One WAVE per doc, lane owns 4 dims: 1 KB coalesced loads per instr.
// ---------------------------------------------------------------------------
__global__ __launch_bounds__(256) void k1_docavg(
    const float* __restrict__ sent, const int* __restrict__ dls,
    float* __restrict__ docs)
{
    int wave = threadIdx.x >> 6;
    int lane = threadIdx.x & 63;
    int b = blockIdx.x * 4 + wave;
    int dl = dls[b];
    const float4* p = (const float4*)(sent + (size_t)b * L * D) + lane;
    float4 s = make_float4(0.f, 0.f, 0.f, 0.f);
    int t = 0;
    for (; t + 2 <= dl; t += 2) {
        float4 a = p[(size_t)t * (D / 4)];
        float4 c = p[(size_t)(t + 1) * (D / 4)];
        s.x += a.x + c.x; s.y += a.y + c.y;
        s.z += a.z + c.z; s.w += a.w + c.w;
    }
    if (t < dl) {
        float4 a = p[(size_t)t * (D / 4)];
        s.x += a.x; s.y += a.y; s.z += a.z; s.w += a.w;
    }
    float inv = 1.0f / (float)dl;
    float4 r = make_float4(s.x * inv, s.y * inv, s.z * inv, s.w * inv);
    ((float4*)(docs + (size_t)b * D))[lane] = r;
}

// ---------------------------------------------------------------------------
// K2: doc = tanh(docs @ fc_w.T + fc_b); uw = W_sal @ doc + w_content
// ---------------------------------------------------------------------------
__global__ __launch_bounds__(256) void k2_docrep(
    const float* __restrict__ docs, const float* __restrict__ fc_w,
    const float* __restrict__ fc_b, const float* __restrict__ W_sal,
    const float* __restrict__ w_content, float* __restrict__ uw)
{
    __shared__ float sd[8][D];
    __shared__ float sdoc[8][D];
    int g = blockIdx.x;
    int i = threadIdx.x;

    for (int dd = 0; dd < 8; dd++) sd[dd][i] = docs[(size_t)(g * 8 + dd) * D + i];
    __syncthreads();

    float acc[8];
    float fb = fc_b[i];
#pragma unroll
    for (int dd = 0; dd < 8; dd++) acc[dd] = fb;
    const float4* wr = (const float4*)(fc_w + (size_t)i * D);
    for (int j = 0; j < D / 4; j++) {
        float4 w = wr[j];
#pragma unroll
        for (int dd = 0; dd < 8; dd++) {
            float4 v = ((const float4*)sd[dd])[j];
            acc[dd] += w.x * v.x + w.y * v.y + w.z * v.z + w.w * v.w;
        }
    }
#pragma unroll
    for (int dd = 0; dd < 8; dd++) sdoc[dd][i] = tanhf(acc[dd]);
    __syncthreads();

    float acc2[8];
#pragma unroll
    for (int dd = 0; dd < 8; dd++) acc2[dd] = 0.f;
    const float4* wsr = (const float4*)(W_sal + (size_t)i * D);
    for (int j = 0; j < D / 4; j++) {
        float4 w = wsr[j];
#pragma unroll
        for (int dd = 0; dd < 8; dd++) {
            float4 v = ((const float4*)sdoc[dd])[j];
            acc2[dd] += w.x * v.x + w.y * v.y + w.z * v.z + w.w * v.w;
        }
    }
    float wc = w_content[i];
#pragma unroll
    for (int dd = 0; dd < 8; dd++)
        uw[(size_t)(g * 8 + dd) * D + i] = acc2[dd] + wc;
}

// ---------------------------------------------------------------------------
// K3: G(fp32) = sent @ W_nov via split-fp16 MFMA (hi*hi + hi*lo + lo*hi).
//     Async-pipelined: A-tile (fp32, 128x64, 32 KB) staged via
//     global_load_lds width-16, double-buffered, counted vmcnt(8) at the
//     barrier (next tile's loads stay in flight across compute).
//     LDS XOR-swizzled at 16B granules (u ^= r&7): linear dest +
//     pre-swizzled global source + swizzled read (rule 21).
//     fp32->fp16 split happens at fragment read (register side).
//     B fragments preloaded into regs BEFORE the staging issue so the
//     compiler's B-wait is vmcnt(8), not vmcnt(0).
//     Accumulation order identical to round-0 -> bit-identical G.
// ---------------------------------------------------------------------------
__global__ __launch_bounds__(256, 2) void k3_mfma(
    const float* __restrict__ A, const _Float16* __restrict__ Wh,
    const _Float16* __restrict__ Wl, float* __restrict__ G)
{
    __shared__ __align__(16) float As[2][128 * 64];   // 2 x 32 KB fp32

    int tid = threadIdx.x;
    int lane = tid & 63;
    int wv = tid >> 6;
    int n0 = blockIdx.x * 128;           // gridDim.x = 2
    int m0 = blockIdx.y * 128;
    int m_off = (wv & 1) * 64;
    int n_off = (wv >> 1) * 64;
    int quad = lane >> 4;
    int l15 = lane & 15;

    f32x4 acc[4][4];
#pragma unroll
    for (int fi = 0; fi < 4; fi++)
#pragma unroll
        for (int fj = 0; fj < 4; fj++) acc[fi][fj] = (f32x4){0.f, 0.f, 0.f, 0.f};

    half8 bhr[2][4], blr[2][4];

    // stage window w (k floats w*64..w*64+63) into buffer bf.
    // LDS granule (r,u) <- global granule (r, u ^ (r&7)); dest linear.
#define STAGE(bf, w)                                                          \
    {                                                                         \
        _Pragma("unroll")                                                     \
        for (int i = 0; i < 8; i++) {                                         \
            int flat = i * 256 + tid;        /* 16B granule 0..2047 */        \
            int r = flat >> 4, u = flat & 15;                                 \
            int us = u ^ (r & 7);                                             \
            const float* src = A + (size_t)(m0 + r) * D + (w) * 64 + us * 4;  \
            float* dst = &As[bf][(i * 256 + wv * 64) * 4];                    \
            __builtin_amdgcn_global_load_lds(                                 \
                (const __attribute__((address_space(1))) void*)src,           \
                (__attribute__((address_space(3))) void*)dst, 16, 0, 0);      \
        }                                                                     \
    }

#define LOADB(w)                                                              \
    {                                                                         \
        _Pragma("unroll")                                                     \
        for (int ks = 0; ks < 2; ks++)                                        \
            _Pragma("unroll")                                                 \
            for (int fj = 0; fj < 4; fj++) {                                  \
                size_t wo = (size_t)(n0 + n_off + fj * 16 + l15) * D          \
                          + (w) * 64 + ks * 32 + quad * 8;                    \
                bhr[ks][fj] = *(const half8*)(Wh + wo);                       \
                blr[ks][fj] = *(const half8*)(Wl + wo);                       \
            }                                                                 \
    }

#define COMPUTE(bf)                                                           \
    {                                                                         \
        _Pragma("unroll")                                                     \
        for (int ks = 0; ks < 2; ks++) {                                      \
            int gq = ks * 4 + quad;                                           \
            half8 ah[4], al[4];                                               \
            _Pragma("unroll")                                                 \
            for (int fi = 0; fi < 4; fi++) {                                  \
                int r = m_off + fi * 16 + l15;                                \
                const float4* Ar = (const float4*)&As[bf][r * 64];            \
                float4 v0 = Ar[(gq * 2) ^ (r & 7)];                           \
                float4 v1 = Ar[(gq * 2 + 1) ^ (r & 7)];                       \
                float f[8] = {v0.x, v0.y, v0.z, v0.w,                         \
                              v1.x, v1.y, v1.z, v1.w};                        \
                _Pragma("unroll")                                             \
                for (int j = 0; j < 8; j++) {                                 \
                    _Float16 h = (_Float16)f[j];                              \
                    ah[fi][j] = h;                                            \
                    al[fi][j] = (_Float16)(f[j] - (float)h);                  \
                }                                                             \
            }                                                                 \
            _Pragma("unroll")                                                 \
            for (int fi = 0; fi < 4; fi++)                                    \
                _Pragma("unroll")                                             \
                for (int fj = 0; fj < 4; fj++) {                              \
                    acc[fi][fj] = __builtin_amdgcn_mfma_f32_16x16x32_f16(     \
                        ah[fi], bhr[ks][fj], acc[fi][fj], 0, 0, 0);           \
                    acc[fi][fj] = __builtin_amdgcn_mfma_f32_16x16x32_f16(     \
                        ah[fi], blr[ks][fj], acc[fi][fj], 0, 0, 0);           \
                    acc[fi][fj] = __builtin_amdgcn_mfma_f32_16x16x32_f16(     \
                        al[fi], bhr[ks][fj], acc[fi][fj], 0, 0, 0);           \
                }                                                             \
        }                                                                     \
    }

    STAGE(0, 0);                 // 8 loads in flight
    LOADB(0);                    // 16 B loads (L2-hot)
    STAGE(1, 1);                 // +8: next tile prefetch
    asm volatile("s_waitcnt vmcnt(8)\n\ts_barrier" ::: "memory");
    __builtin_amdgcn_sched_barrier(0);
    COMPUTE(0);                  // window 0; stage(1) in flight under MFMA

    asm volatile("s_barrier" ::: "memory");
    LOADB(1);
    STAGE(0, 2);
    asm volatile("s_waitcnt vmcnt(8)\n\ts_barrier" ::: "memory");
    __builtin_amdgcn_sched_barrier(0);
    COMPUTE(1);

    asm volatile("s_barrier" ::: "memory");
    LOADB(2);
    STAGE(1, 3);
    asm volatile("s_waitcnt vmcnt(8)\n\ts_barrier" ::: "memory");
    __builtin_amdgcn_sched_barrier(0);
    COMPUTE(0);

    asm volatile("s_barrier" ::: "memory");
    LOADB(3);
    // oldest 8 outstanding (= stage(3)) must drain; B(3) may stay in flight
    asm volatile("s_waitcnt vmcnt(16)\n\ts_barrier" ::: "memory");
    __builtin_amdgcn_sched_barrier(0);
    COMPUTE(1);

#undef STAGE
#undef LOADB
#undef COMPUTE

    // ---- epilogue: direct fp32 stores (C layout: row=quad*4+q, col=l15) ----
#pragma unroll
    for (int fi = 0; fi < 4; fi++)
#pragma unroll
        for (int fj = 0; fj < 4; fj++)
#pragma unroll
            for (int q = 0; q < 4; q++) {
                int row = m0 + m_off + fi * 16 + quad * 4 + q;
                int col = n0 + n_off + fj * 16 + l15;
                G[(size_t)row * D + col] = acc[fi][fj][q];
            }
}

// ---------------------------------------------------------------------------
// K4: recurrence. One wave per doc; lane l owns dims 4l..4l+3 of s.
//     Depth-4 prefetch with static register pairs; tail predicated.
// ---------------------------------------------------------------------------
__global__ __launch_bounds__(256) void k4_recur(
    const float* __restrict__ sent, const float* __restrict__ G,
    const float* __restrict__ uw, const float* __restrict__ abs_w,
    const float* __restrict__ relw, const float* __restrict__ bias,
    const int* __restrict__ dls, const int* __restrict__ offs,
    float* __restrict__ out)
{
    int wave = threadIdx.x >> 6;
    int lane = threadIdx.x & 63;
    int b = blockIdx.x * 4 + wave;

    int dl = dls[b];
    float dlf = (float)dl;
    int base = offs[b];
    float bs = bias[0];

    const float4* h_ptr = (const float4*)(sent + (size_t)b * L * D) + lane;
    const float4* g_ptr = (const float4*)(G + (size_t)b * L * D) + lane;
    float4 uwv = ((const float4*)(uw + (size_t)b * D))[lane];

    float4 s = make_float4(0.f, 0.f, 0.f, 0.f);

    float4 h0 = h_ptr[0 * (D / 4)], g0 = g_ptr[0 * (D / 4)];
    float4 h1 = h_ptr[1 * (D / 4)], g1 = g_ptr[1 * (D / 4)];
    float4 h2 = h_ptr[2 * (D / 4)], g2 = g_ptr[2 * (D / 4)];
    float4 h3 = h_ptr[3 * (D / 4)], g3 = g_ptr[3 * (D / 4)];

#define STEP(HH, GG, TT)                                                     \
    {                                                                        \
        int tt = (TT);                                                       \
        int tp = tt + 4; if (tp >= L) tp = 0;                                \
        float4 hn = h_ptr[(size_t)tp * (D / 4)];                             \
        float4 gn = g_ptr[(size_t)tp * (D / 4)];                             \
        float4 ts;                                                           \
        ts.x = tanhf(s.x); ts.y = tanhf(s.y);                                \
        ts.z = tanhf(s.z); ts.w = tanhf(s.w);                                \
        float r = HH.x * uwv.x + HH.y * uwv.y + HH.z * uwv.z + HH.w * uwv.w  \
                - (GG.x * ts.x + GG.y * ts.y + GG.z * ts.z + GG.w * ts.w);   \
        r += __shfl_xor(r, 32, 64);                                          \
        r += __shfl_xor(r, 16, 64);                                          \
        r += __shfl_xor(r, 8, 64);                                           \
        r += __shfl_xor(r, 4, 64);                                           \
        r += __shfl_xor(r, 2, 64);                                           \
        r += __shfl_xor(r, 1, 64);                                           \
        bool valid = tt < dl;                                                \
        int ta = valid ? tt : 0;                                             \
        int idx = (int)rintf((float)(tt + 1) * 9.0f / dlf);                  \
        if (idx > 24) idx = 24;                                              \
        float pre = r + abs_w[ta] + relw[idx] + bs;                          \
        float p = 1.0f / (1.0f + __expf(-pre));                              \
        float pm = valid ? p : 0.0f;                                         \
        s.x += pm * HH.x; s.y += pm * HH.y;                                  \
        s.z += pm * HH.z; s.w += pm * HH.w;                                  \
        if (valid && lane == 0) out[base + tt] = p;                          \
        HH = hn; GG = gn;                                                    \
    }

    int nsteps = (dl + 3) & ~3;
    for (int t = 0; t < nsteps; t += 4) {
        STEP(h0, g0, t);
        STEP(h1, g1, t + 1);
        STEP(h2, g2, t + 2);
        STEP(h3, g3, t + 3);
    }
#undef STEP
}

// ---------------------------------------------------------------------------
extern "C" void kernel_launch(void* const* d_in, const int* in_sizes, int n_in,
                              void* d_out, int out_size, void* d_ws, size_t ws_size,
                              hipStream_t stream)
{
    const float* sent      = (const float*)d_in[0];
    const float* fc_w      = (const float*)d_in[1];
    const float* fc_b      = (const float*)d_in[2];
    const float* w_content = (const float*)d_in[3];
    const float* W_sal     = (const float*)d_in[4];
    const float* W_nov     = (const float*)d_in[5];
    const float* abs_embed = (const float*)d_in[6];
    const float* rel_embed = (const float*)d_in[7];
    const float* w_abs     = (const float*)d_in[8];
    const float* w_rel     = (const float*)d_in[9];
    const float* bias      = (const float*)d_in[10];
    const int*   dls       = (const int*)d_in[11];
    float* out = (float*)d_out;

    // workspace layout (bytes)
    char* ws = (char*)d_ws;
    int*      offs  = (int*)ws;                                   // 8 KiB
    float*    abs_w = (float*)(ws + 8192);                        // 512 B
    float*    relw  = (float*)(ws + 8704);                        // 512 B
    float*    docs  = (float*)(ws + 9216);                        // 2 MiB
    float*    uw    = (float*)(ws + 9216 + (size_t)B * D * 4);    // 2 MiB
    _Float16* Wh    = (_Float16*)(ws + 9216 + 2 * (size_t)B * D * 4);          // 128 KiB
    _Float16* Wl    = (_Float16*)(ws + 9216 + 2 * (size_t)B * D * 4 + 131072); // 128 KiB
    float*    G     = (float*)(ws + 9216 + 2 * (size_t)B * D * 4 + 262144);    // 200 MiB

    hipLaunchKernelGGL(k0_precompute, dim3(1), dim3(256), 0, stream,
                       abs_embed, w_abs, rel_embed, w_rel, dls, abs_w, relw, offs);
    hipLaunchKernelGGL(k0b_wt, dim3(D), dim3(D), 0, stream, W_nov, Wh, Wl);
    hipLaunchKernelGGL(k1_docavg, dim3(B / 4), dim3(256), 0, stream, sent, dls, docs);
    hipLaunchKernelGGL(k2_docrep, dim3(B / 8), dim3(256), 0, stream,
                       docs, fc_w, fc_b, W_sal, w_content, uw);
    hipLaunchKernelGGL(k3_mfma, dim3(2, (B * L) / 128), dim3(256), 0, stream,
                       sent, Wh, Wl, G);
    hipLaunchKernelGGL(k4_recur, dim3(B / 4), dim3(256), 0, stream,
                       sent, G, uw, abs_w, relw, bias, dls, offs, out);
}